// Round 11
// baseline (90.730 us; speedup 1.0000x reference)
//
#include <hip/hip_runtime.h>
#include <hip/hip_bf16.h>
#include <stdint.h>

typedef __attribute__((ext_vector_type(8))) short bf16x8;
typedef __attribute__((ext_vector_type(4))) float f32x4;

__device__ __forceinline__ short f2bf(float x) {
    __hip_bfloat16 h = __float2bfloat16(x);   // native cvt on gfx950 (RNE)
    return __builtin_bit_cast(short, h);
}

__device__ __forceinline__ bf16x8 pack8(f32x4 a, f32x4 b) {
    bf16x8 r;
    r[0] = f2bf(a[0]); r[1] = f2bf(a[1]); r[2] = f2bf(a[2]); r[3] = f2bf(a[3]);
    r[4] = f2bf(b[0]); r[5] = f2bf(b[1]); r[6] = f2bf(b[2]); r[7] = f2bf(b[3]);
    return r;
}

// ---------------------------------------------------------------------------
// Kernel C: repack Wq (1024x48 f32) into bf16 B-fragment layout.
// ---------------------------------------------------------------------------
__global__ __launch_bounds__(256) void prep_wfrag(const float* __restrict__ Wq,
                                                  short* __restrict__ wfrag) {
    int idx = blockIdx.x * 256 + threadIdx.x;   // 0..49151
    int j    = idx & 7;
    int lane = (idx >> 3) & 63;
    int grp  = idx >> 9;          // ks*3+nf
    int nf   = grp % 3;
    int ks   = grp / 3;
    int k = ks * 32 + ((lane >> 4) << 3) + j;
    int n = nf * 16 + (lane & 15);
    wfrag[idx] = f2bf(Wq[k * 48 + n]);
}

// ---------------------------------------------------------------------------
// Kernel A: qk = Q @ Wq + bq  (M=32768, N=48, K=1024), MFMA 16x16x32 bf16.
// Epilogue scatter-stores bf16 weights into A-frag layout:
//   wgtA[b][k][dg(128)][h(16)][8]
// ---------------------------------------------------------------------------
__global__ __launch_bounds__(256) void qk_gemm(const float* __restrict__ Q,
                                               const short* __restrict__ wfrag,
                                               const float* __restrict__ bq,
                                               short* __restrict__ wgtA) {
    const int l  = threadIdx.x & 63;
    const int w  = threadIdx.x >> 6;
    const int lr = l & 15;
    const int lk = l >> 4;
    const int row0 = blockIdx.x * 64 + w * 16;

    f32x4 acc[3];
    acc[0] = (f32x4){0.f, 0.f, 0.f, 0.f};
    acc[1] = acc[0];
    acc[2] = acc[0];

    const float* qbase = Q + (size_t)(row0 + lr) * 1024 + lk * 8;

    #pragma unroll 4
    for (int ks = 0; ks < 32; ++ks) {
        const float* p = qbase + ks * 32;
        f32x4 q0 = *(const f32x4*)p;
        f32x4 q1 = *(const f32x4*)(p + 4);
        bf16x8 a = pack8(q0, q1);
        const bf16x8* wp = (const bf16x8*)(wfrag + (size_t)ks * 1536 + l * 8);
        acc[0] = __builtin_amdgcn_mfma_f32_16x16x32_bf16(a, wp[0],   acc[0], 0, 0, 0);
        acc[1] = __builtin_amdgcn_mfma_f32_16x16x32_bf16(a, wp[64],  acc[1], 0, 0, 0);
        acc[2] = __builtin_amdgcn_mfma_f32_16x16x32_bf16(a, wp[128], acc[2], 0, 0, 0);
    }

    #pragma unroll
    for (int nf = 0; nf < 3; ++nf) {
        int n = nf * 16 + lr;
        float bias = bq[n];
        int t  = n / 3;
        int kk = n - t * 3;
        #pragma unroll
        for (int r = 0; r < 4; ++r) {
            int row = row0 + lk * 4 + r;
            int b   = row >> 10;
            int h   = (row >> 6) & 15;
            int sp  = row & 63;
            int dg  = sp * 2 + (t >> 3);
            int j   = t & 7;
            wgtA[(((size_t)(b * 3 + kk) * 128 + dg) << 7) + h * 8 + j] = f2bf(acc[nf][r] + bias);
        }
    }
}

// ---------------------------------------------------------------------------
// Kernel B v11: REGISTER-STREAMING conv. No LDS staging, no loop barriers.
// B-frag is per-lane rows (no transpose needed): lane(lr,lk) tap k reads
// key[s+k-1][dh*512 + t*32 + lk*8 .. +7] -- 3 sequential 128B-stride streams
// per lane; L1 absorbs the 3x tap overlap across lanes. Hand-pipelined
// depth-2 with NAMED register sets (static indexing); consume-before-reload
// keeps the other set's loads in flight across each MFMA wait.
// Grid 1024 (32 b x 32 st) XCD-swizzled, 256 thr: ss=w&1 (s-sub 16),
// dh=w>>1 (d-half 512). 16 iters x 32 d. d-halves combined via tiny LDS.
// ---------------------------------------------------------------------------
__global__ __launch_bounds__(256, 4) void conv_mfma(const float* __restrict__ Key,
                                                    const short* __restrict__ wgtA,
                                                    float* __restrict__ out) {
    __shared__ float red[2][16][17];
    const int blk = (blockIdx.x & 7) * 128 + (blockIdx.x >> 3);  // XCD swizzle
    const int st  = blk & 31;
    const int b   = blk >> 5;
    const int tid = threadIdx.x;
    const int l   = tid & 63;
    const int w   = tid >> 6;
    const int lr  = l & 15;
    const int lk  = l >> 4;
    const int ss  = w & 1;
    const int dh  = w >> 1;
    const int s   = (st << 5) + (ss << 4) + lr;

    const bool ok0 = (s > 0);
    const bool ok2 = (s < 1023);
    const float* keyB = Key + ((size_t)b << 20) + (dh << 9) + (lk << 3);
    const f32x4* pk0 = (const f32x4*)(keyB + (size_t)(ok0 ? s - 1 : 0) * 1024);
    const f32x4* pk1 = (const f32x4*)(keyB + (size_t)s * 1024);
    const f32x4* pk2 = (const f32x4*)(keyB + (size_t)(ok2 ? s + 1 : 1023) * 1024);
    const short* wgtW = wgtA + (((size_t)b * 384 + (dh << 6) + lk) << 7) + lr * 8;

    const f32x4 z4 = (f32x4){0.f, 0.f, 0.f, 0.f};
    f32x4 a00, a01, a10, a11, a20, a21;    // key set A (3 taps x 32B)
    f32x4 b00, b01, b10, b11, b20, b21;    // key set B
    bf16x8 wa0, wa1, wa2, wb0, wb1, wb2;   // wgt sets
    f32x4 acc = z4;

    #define KLOAD(S, tt) do{ \
        S##00 = pk0[(tt) * 8];  S##01 = pk0[(tt) * 8 + 1]; \
        S##10 = pk1[(tt) * 8];  S##11 = pk1[(tt) * 8 + 1]; \
        S##20 = pk2[(tt) * 8];  S##21 = pk2[(tt) * 8 + 1]; }while(0)

    #define WLOAD(S, tt) do{ \
        w##S##0 = *(const bf16x8*)(wgtW +         (tt) * 512); \
        w##S##1 = *(const bf16x8*)(wgtW + 16384 + (tt) * 512); \
        w##S##2 = *(const bf16x8*)(wgtW + 32768 + (tt) * 512); }while(0)

    #define CONSUME(S) do{ \
        f32x4 t00 = ok0 ? S##00 : z4, t01 = ok0 ? S##01 : z4; \
        f32x4 t20 = ok2 ? S##20 : z4, t21 = ok2 ? S##21 : z4; \
        acc = __builtin_amdgcn_mfma_f32_16x16x32_bf16(w##S##0, pack8(t00, t01),     acc, 0, 0, 0); \
        acc = __builtin_amdgcn_mfma_f32_16x16x32_bf16(w##S##1, pack8(S##10, S##11), acc, 0, 0, 0); \
        acc = __builtin_amdgcn_mfma_f32_16x16x32_bf16(w##S##2, pack8(t20, t21),     acc, 0, 0, 0); }while(0)

    // prologue: both sets in flight
    KLOAD(a, 0);  WLOAD(a, 0);
    KLOAD(b, 1);  WLOAD(b, 1);

    #pragma unroll
    for (int t = 0; t < 16; t += 2) {
        CONSUME(a);                                   // waits set A only; set B stays in flight
        if (t + 2 < 16) { KLOAD(a, t + 2); WLOAD(a, t + 2); }
        CONSUME(b);
        if (t + 3 < 16) { KLOAD(b, t + 3); WLOAD(b, t + 3); }
    }
    #undef KLOAD
    #undef WLOAD
    #undef CONSUME

    // combine d-halves (single barrier in whole kernel)
    if (dh == 1) {
        #pragma unroll
        for (int r4 = 0; r4 < 4; ++r4) red[ss][lk * 4 + r4][lr] = acc[r4];
    }
    __syncthreads();
    if (dh == 0) {
        #pragma unroll
        for (int r4 = 0; r4 < 4; ++r4) {
            int h = lk * 4 + r4;
            out[(((b << 4) + h) << 10) + s] = acc[r4] + red[ss][h][lr];
        }
    }
}

extern "C" void kernel_launch(void* const* d_in, const int* in_sizes, int n_in,
                              void* d_out, int out_size, void* d_ws, size_t ws_size,
                              hipStream_t stream) {
    const float* Q  = (const float*)d_in[0];
    const float* K  = (const float*)d_in[1];
    const float* Wq = (const float*)d_in[4];
    const float* bq = (const float*)d_in[5];
    float* outp = (float*)d_out;

    short* wfrag = (short*)d_ws;                      // 98304 B
    short* wgtA  = (short*)((char*)d_ws + 98304);     // 3145728 B

    hipLaunchKernelGGL(prep_wfrag, dim3(192),  dim3(256), 0, stream, Wq, wfrag);
    hipLaunchKernelGGL(qk_gemm,    dim3(512),  dim3(256), 0, stream, Q, wfrag, bq, wgtA);
    hipLaunchKernelGGL(conv_mfma,  dim3(1024), dim3(256), 0, stream, K, wgtA, outp);
}

// Round 12
// 62.713 us; speedup vs baseline: 1.4467x; 1.4467x over previous
//
#include <hip/hip_runtime.h>
#include <hip/hip_bf16.h>
#include <stdint.h>

typedef __attribute__((ext_vector_type(8))) short bf16x8;
typedef __attribute__((ext_vector_type(4))) float f32x4;

__device__ __forceinline__ short f2bf(float x) {
    __hip_bfloat16 h = __float2bfloat16(x);   // native cvt on gfx950 (RNE)
    return __builtin_bit_cast(short, h);
}

__device__ __forceinline__ bf16x8 pack8(f32x4 a, f32x4 b) {
    bf16x8 r;
    r[0] = f2bf(a[0]); r[1] = f2bf(a[1]); r[2] = f2bf(a[2]); r[3] = f2bf(a[3]);
    r[4] = f2bf(b[0]); r[5] = f2bf(b[1]); r[6] = f2bf(b[2]); r[7] = f2bf(b[3]);
    return r;
}

// 4B-granule HBM->LDS DMA: dest = wave-uniform base + lane*4
#define GLDS4(gp, lp) __builtin_amdgcn_global_load_lds( \
    (const __attribute__((address_space(1))) void*)(gp), \
    (__attribute__((address_space(3))) void*)(lp), 4, 0, 0)

// ---------------------------------------------------------------------------
// Kernel C: repack Wq (1024x48 f32) into bf16 B-fragment layout.
// ---------------------------------------------------------------------------
__global__ __launch_bounds__(256) void prep_wfrag(const float* __restrict__ Wq,
                                                  short* __restrict__ wfrag) {
    int idx = blockIdx.x * 256 + threadIdx.x;   // 0..49151
    int j    = idx & 7;
    int lane = (idx >> 3) & 63;
    int grp  = idx >> 9;          // ks*3+nf
    int nf   = grp % 3;
    int ks   = grp / 3;
    int k = ks * 32 + ((lane >> 4) << 3) + j;
    int n = nf * 16 + (lane & 15);
    wfrag[idx] = f2bf(Wq[k * 48 + n]);
}

// ---------------------------------------------------------------------------
// Kernel A: qk = Q @ Wq + bq  (M=32768, N=48, K=1024), MFMA 16x16x32 bf16.
// Epilogue scatter-stores bf16 weights into A-frag layout:
//   wgtA[b][k][dg(128)][h(16)][8]
// ---------------------------------------------------------------------------
__global__ __launch_bounds__(256) void qk_gemm(const float* __restrict__ Q,
                                               const short* __restrict__ wfrag,
                                               const float* __restrict__ bq,
                                               short* __restrict__ wgtA) {
    const int l  = threadIdx.x & 63;
    const int w  = threadIdx.x >> 6;
    const int lr = l & 15;
    const int lk = l >> 4;
    const int row0 = blockIdx.x * 64 + w * 16;

    f32x4 acc[3];
    acc[0] = (f32x4){0.f, 0.f, 0.f, 0.f};
    acc[1] = acc[0];
    acc[2] = acc[0];

    const float* qbase = Q + (size_t)(row0 + lr) * 1024 + lk * 8;

    #pragma unroll 4
    for (int ks = 0; ks < 32; ++ks) {
        const float* p = qbase + ks * 32;
        f32x4 q0 = *(const f32x4*)p;
        f32x4 q1 = *(const f32x4*)(p + 4);
        bf16x8 a = pack8(q0, q1);
        const bf16x8* wp = (const bf16x8*)(wfrag + (size_t)ks * 1536 + l * 8);
        acc[0] = __builtin_amdgcn_mfma_f32_16x16x32_bf16(a, wp[0],   acc[0], 0, 0, 0);
        acc[1] = __builtin_amdgcn_mfma_f32_16x16x32_bf16(a, wp[64],  acc[1], 0, 0, 0);
        acc[2] = __builtin_amdgcn_mfma_f32_16x16x32_bf16(a, wp[128], acc[2], 0, 0, 0);
    }

    #pragma unroll
    for (int nf = 0; nf < 3; ++nf) {
        int n = nf * 16 + lr;
        float bias = bq[n];
        int t  = n / 3;
        int kk = n - t * 3;
        #pragma unroll
        for (int r = 0; r < 4; ++r) {
            int row = row0 + lk * 4 + r;
            int b   = row >> 10;
            int h   = (row >> 6) & 15;
            int sp  = row & 63;
            int dg  = sp * 2 + (t >> 3);
            int j   = t & 7;
            wgtA[(((size_t)(b * 3 + kk) * 128 + dg) << 7) + h * 8 + j] = f2bf(acc[nf][r] + bias);
        }
    }
}

// ---------------------------------------------------------------------------
// Kernel B v12: wave-private global_load_lds pipelines, counted vmcnt,
// ZERO barriers in main loop. Grid 1024 (32b x 32st) XCD-swizzled, 256 thr:
// ss=w&1 (16 s-rows), dh=w>>1 (512-d half). 16 steps x 32 d.
// Per wave per step: 9x GLDS4 (18 rows x 128B, its d-half) into a private
// 4-buffer LDS ring; A-frags parity-prefetched 1 step ahead in registers.
// vmcnt derived from issue order (prologue S0,A0,S1,S2; step t issues
// A(t+1) then S(t+3)): t0=30, t1..12=21, t13=12, t14=3, t15=0.
// Read-side XOR swizzle ((row&7)<<4) + inverse-swizzled global source.
// ---------------------------------------------------------------------------
__global__ __launch_bounds__(256, 4) void conv_mfma(const float* __restrict__ Key,
                                                    const short* __restrict__ wgtA,
                                                    float* __restrict__ out) {
    __shared__ char klds[4][4 * 2304];    // [wave][ring buf*2304]
    __shared__ float red[2][16][17];
    const int blk = (blockIdx.x & 7) * 128 + (blockIdx.x >> 3);  // XCD swizzle
    const int st  = blk & 31;
    const int b   = blk >> 5;
    const int tid = threadIdx.x;
    const int l   = tid & 63;
    const int w   = tid >> 6;
    const int lr  = l & 15;
    const int lk  = l >> 4;
    const int ss  = w & 1;
    const int dh  = w >> 1;
    const int sbase = (st << 5) + (ss << 4);

    // staging sources: instr i covers rows 2i,2i+1 (128B each, this d-half).
    // lane row = 2i + (l>>5); lane slot cb = (l&31)*4; global byte = cb ^ swz.
    const char* gaddr[9];
    {
        const char* keyB = (const char*)Key + ((size_t)b << 22) + (dh << 11);
        const int cb = (l & 31) << 2;
        #pragma unroll
        for (int i = 0; i < 9; ++i) {
            int grow = 2 * i + (l >> 5);              // 0..17
            int srow = sbase - 1 + grow;
            srow = srow < 0 ? 0 : (srow > 1023 ? 1023 : srow);
            gaddr[i] = keyB + (size_t)srow * 4096 + (cb ^ ((grow & 7) << 4));
        }
    }
    char* ldsW = &klds[w][0];
    const bool zlo = (st == 0  && ss == 0);   // row 0  invalid (s=-1)
    const bool zhi = (st == 31 && ss == 1);   // row 17 invalid (s=1024)

    const short* wgtW = wgtA + (((size_t)b * 384 + (dh << 6) + lk) << 7) + lr * 8;
    bf16x8 awA[3], awB[3];
    f32x4 acc = (f32x4){0.f, 0.f, 0.f, 0.f};
    const f32x4 z4 = acc;

    #define ALOADV(arr, tt) do{ _Pragma("unroll") \
        for (int k3 = 0; k3 < 3; ++k3) \
            arr[k3] = *(const bf16x8*)(wgtW + k3 * 16384 + (tt) * 512); }while(0)

    #define STAGEV(tt) do{ char* bb_ = ldsW + ((tt) & 3) * 2304; _Pragma("unroll") \
        for (int i9 = 0; i9 < 9; ++i9) GLDS4(gaddr[i9] + (tt) * 128, bb_ + i9 * 256); }while(0)

    #define WAITV(N) do{ asm volatile("s_waitcnt vmcnt(" N ")" ::: "memory"); \
        __builtin_amdgcn_sched_barrier(0); }while(0)

    #define ZFIXW(tt) do{ \
        if (zlo && l < 8) *(f32x4*)(ldsW + ((tt) & 3) * 2304 + (l << 4)) = z4; \
        if (zhi && l < 8) *(f32x4*)(ldsW + ((tt) & 3) * 2304 + 17 * 128 + (l << 4)) = z4; }while(0)

    #define COMP(tt) do{ \
        const char* bb_ = ldsW + ((tt) & 3) * 2304; \
        _Pragma("unroll") for (int k3 = 0; k3 < 3; ++k3) { \
            int row_ = lr + k3; \
            const char* rb_ = bb_ + row_ * 128; \
            int sw_ = (row_ & 7) << 4; \
            int x_  = lk << 5; \
            f32x4 v0_ = *(const f32x4*)(rb_ + (x_ ^ sw_)); \
            f32x4 v1_ = *(const f32x4*)(rb_ + ((x_ + 16) ^ sw_)); \
            bf16x8 a_ = ((tt) & 1) ? awB[k3] : awA[k3]; \
            acc = __builtin_amdgcn_mfma_f32_16x16x32_bf16(a_, pack8(v0_, v1_), acc, 0, 0, 0); \
        } }while(0)

    #define STEP(tt, NV) do{ \
        if ((tt) < 15) { if ((tt) & 1) ALOADV(awA, (tt) + 1); else ALOADV(awB, (tt) + 1); } \
        if ((tt) < 13) STAGEV((tt) + 3); \
        WAITV(NV); \
        ZFIXW(tt); \
        COMP(tt); }while(0)

    // prologue: S0, A0, S1, S2  (A0 early so its wait only needs 30-newer)
    STAGEV(0);
    ALOADV(awA, 0);
    STAGEV(1);
    STAGEV(2);

    STEP(0,  "30");  STEP(1,  "21");  STEP(2,  "21");  STEP(3,  "21");
    STEP(4,  "21");  STEP(5,  "21");  STEP(6,  "21");  STEP(7,  "21");
    STEP(8,  "21");  STEP(9,  "21");  STEP(10, "21");  STEP(11, "21");
    STEP(12, "21");  STEP(13, "12");  STEP(14, "3");   STEP(15, "0");

    #undef ALOADV
    #undef STAGEV
    #undef WAITV
    #undef ZFIXW
    #undef COMP
    #undef STEP

    // combine d-halves (single barrier in whole kernel)
    if (dh == 1) {
        #pragma unroll
        for (int r4 = 0; r4 < 4; ++r4) red[ss][lk * 4 + r4][lr] = acc[r4];
    }
    __syncthreads();
    if (dh == 0) {
        const int s = sbase + lr;
        #pragma unroll
        for (int r4 = 0; r4 < 4; ++r4) {
            int h = lk * 4 + r4;
            out[(((b << 4) + h) << 10) + s] = acc[r4] + red[ss][h][lr];
        }
    }
}

extern "C" void kernel_launch(void* const* d_in, const int* in_sizes, int n_in,
                              void* d_out, int out_size, void* d_ws, size_t ws_size,
                              hipStream_t stream) {
    const float* Q  = (const float*)d_in[0];
    const float* K  = (const float*)d_in[1];
    const float* Wq = (const float*)d_in[4];
    const float* bq = (const float*)d_in[5];
    float* outp = (float*)d_out;

    short* wfrag = (short*)d_ws;                      // 98304 B
    short* wgtA  = (short*)((char*)d_ws + 98304);     // 3145728 B

    hipLaunchKernelGGL(prep_wfrag, dim3(192),  dim3(256), 0, stream, Wq, wfrag);
    hipLaunchKernelGGL(qk_gemm,    dim3(512),  dim3(256), 0, stream, Q, wfrag, bq, wgtA);
    hipLaunchKernelGGL(conv_mfma,  dim3(1024), dim3(256), 0, stream, K, wgtA, outp);
}